// Round 1
// baseline (1069.956 us; speedup 1.0000x reference)
//
#include <hip/hip_runtime.h>
#include <hip/hip_bf16.h>
#include <cstdint>

// Problem constants (fixed by reference)
#define NN 8192
#define HH 256
#define II 128
#define KORD 4
#define EE 262144
#define TBL (1u << 20)   // hash table slots (load factor 0.25)

// ---------------- pos layout handling (int32 vs int64 words) ----------------
__device__ __forceinline__ void read_pos(const int* __restrict__ pos, int flag,
                                         int e, int& r, int& c) {
    if (flag) { r = pos[4 * e]; c = pos[4 * e + 2]; }   // int64 little-endian
    else      { r = pos[2 * e]; c = pos[2 * e + 1]; }   // int32
}

__global__ void detect_layout(const int* __restrict__ pos, int* __restrict__ flag) {
    if (threadIdx.x == 0 && blockIdx.x == 0) {
        int f = 1;
        for (int i = 0; i < 128; ++i) {
            if (pos[2 * i + 1] != 0) { f = 0; break; }
        }
        *flag = f;
    }
}

// ---------------- init ----------------
__global__ void init_ws(uint32_t* __restrict__ hkey, uint32_t* __restrict__ hidx,
                        uint32_t* __restrict__ rcnt) {
    int i = blockIdx.x * blockDim.x + threadIdx.x;
    if (i < (int)TBL) { hkey[i] = 0xFFFFFFFFu; hidx[i] = 0u; }
    if (i < NN) rcnt[i] = 0u;
}

__device__ __forceinline__ uint32_t hash_key(uint32_t key) {
    return (key * 2654435761u) >> 6 & (TBL - 1u);
}

// ---------------- dedupe: last write wins ----------------
__global__ void build_hash(const int* __restrict__ pos, const int* __restrict__ flagp,
                           uint32_t* __restrict__ hkey, uint32_t* __restrict__ hidx) {
    int e = blockIdx.x * blockDim.x + threadIdx.x;
    if (e >= EE) return;
    int flag = *flagp;
    int r, c; read_pos(pos, flag, e, r, c);
    uint32_t key = (uint32_t)r * (uint32_t)NN + (uint32_t)c;
    uint32_t slot = hash_key(key);
    for (;;) {
        uint32_t prev = atomicCAS(&hkey[slot], 0xFFFFFFFFu, key);
        if (prev == 0xFFFFFFFFu || prev == key) {
            atomicMax(&hidx[slot], (uint32_t)(e + 1));
            break;
        }
        slot = (slot + 1u) & (TBL - 1u);
    }
}

__global__ void dedup_vals(const int* __restrict__ pos, const int* __restrict__ flagp,
                           const float* __restrict__ lap,
                           const uint32_t* __restrict__ hkey, const uint32_t* __restrict__ hidx,
                           float* __restrict__ vdd) {
    int e = blockIdx.x * blockDim.x + threadIdx.x;
    if (e >= EE) return;
    int flag = *flagp;
    int r, c; read_pos(pos, flag, e, r, c);
    uint32_t key = (uint32_t)r * (uint32_t)NN + (uint32_t)c;
    uint32_t slot = hash_key(key);
    while (hkey[slot] != key) slot = (slot + 1u) & (TBL - 1u);
    vdd[e] = (hidx[slot] == (uint32_t)(e + 1)) ? lap[e] : 0.0f;
}

// ---------------- CSR build ----------------
__global__ void count_rows(const int* __restrict__ pos, const int* __restrict__ flagp,
                           uint32_t* __restrict__ rcnt) {
    int e = blockIdx.x * blockDim.x + threadIdx.x;
    if (e >= EE) return;
    int flag = *flagp;
    int r, c; read_pos(pos, flag, e, r, c);
    atomicAdd(&rcnt[r], 1u);
}

__global__ __launch_bounds__(1024) void scan_rows(const uint32_t* __restrict__ cnt,
                                                  uint32_t* __restrict__ rptr,
                                                  uint32_t* __restrict__ curs) {
    __shared__ uint32_t part[1024];
    int t = threadIdx.x;
    uint32_t loc[8];
    uint32_t s = 0;
#pragma unroll
    for (int i = 0; i < 8; ++i) { loc[i] = s; s += cnt[t * 8 + i]; }
    part[t] = s;
    __syncthreads();
    for (int o = 1; o < 1024; o <<= 1) {
        uint32_t xv = part[t];
        uint32_t yv = (t >= o) ? part[t - o] : 0u;
        __syncthreads();
        part[t] = xv + yv;
        __syncthreads();
    }
    uint32_t base = part[t] - s;  // exclusive prefix for this thread
#pragma unroll
    for (int i = 0; i < 8; ++i) {
        uint32_t v = base + loc[i];
        rptr[t * 8 + i] = v;
        curs[t * 8 + i] = v;
    }
    if (t == 1023) rptr[NN] = part[1023];
}

__global__ void scatter_csr(const int* __restrict__ pos, const int* __restrict__ flagp,
                            const float* __restrict__ vdd,
                            uint32_t* __restrict__ curs,
                            uint32_t* __restrict__ ccol, float* __restrict__ cval) {
    int e = blockIdx.x * blockDim.x + threadIdx.x;
    if (e >= EE) return;
    int flag = *flagp;
    int r, c; read_pos(pos, flag, e, r, c);
    uint32_t slot = atomicAdd(&curs[r], 1u);
    ccol[slot] = (uint32_t)c;
    cval[slot] = vdd[e];
}

// ---------------- SpMV with fused Chebyshev recurrence ----------------
// Y[r,:] = a * (L @ X)[r,:] + b * Prev[r,:]
template <int F>
__global__ void spmv_cheb(const uint32_t* __restrict__ rptr,
                          const uint32_t* __restrict__ ccol,
                          const float* __restrict__ cval,
                          const float* __restrict__ X,
                          const float* __restrict__ Prev,
                          float* __restrict__ Y, float a, float b) {
    int r = blockIdx.x;
    int t = threadIdx.x;
    uint32_t s = rptr[r], e = rptr[r + 1];
    float acc = 0.0f;
    for (uint32_t i = s; i < e; ++i) {
        float v = cval[i];
        uint32_t c = ccol[i];
        acc += v * X[(size_t)c * F + t];
    }
    float o = a * acc;
    if (b != 0.0f) o += b * Prev[(size_t)r * F + t];
    Y[(size_t)r * F + t] = o;
}

// ---------------- fused gate GEMM + LSTM elementwise ----------------
// preact_g[n,h] = sum_k sum_f Th[k,n,f] Wgh[k,h,f] + sum_k sum_f Tx[k,n,f] Wgx[k,h,f]
// A = [N, 1536] (j<1024: Th, else Tx), B_g[h,j] = W[k,h,f]
#define BM 64
#define BN 64
#define BK 32

__device__ __forceinline__ float sigmoidf_(float x) { return 1.0f / (1.0f + expf(-x)); }

__global__ __launch_bounds__(256) void gemm_lstm(
    const float* __restrict__ Th, const float* __restrict__ Tx,
    const float* __restrict__ Wfh, const float* __restrict__ Wfx,
    const float* __restrict__ Wih, const float* __restrict__ Wix,
    const float* __restrict__ Woh, const float* __restrict__ Wox,
    const float* __restrict__ Wch, const float* __restrict__ Wcx,
    const float* __restrict__ bf, const float* __restrict__ bi,
    const float* __restrict__ bo, const float* __restrict__ bc,
    const float* __restrict__ cin, float* __restrict__ out) {
    __shared__ float As[BK][BM + 1];
    __shared__ float Bs[4][BK][BN + 1];
    int h0 = blockIdx.x * BN;
    int n0 = blockIdx.y * BM;
    int t = threadIdx.x;
    int tx = t & 15, ty = t >> 4;

    float acc[4][4][4];
#pragma unroll
    for (int g = 0; g < 4; ++g)
#pragma unroll
        for (int i = 0; i < 4; ++i)
#pragma unroll
            for (int j = 0; j < 4; ++j) acc[g][i][j] = 0.0f;

    for (int j0 = 0; j0 < KORD * (HH + II); j0 += BK) {
        const float* abase;
        int astr, k, fb, F;
        const float* Wg[4];
        if (j0 < KORD * HH) {
            k = j0 >> 8; fb = j0 & 255; F = HH;
            abase = Th + ((size_t)k * NN) * HH + fb; astr = HH;
            Wg[0] = Wfh; Wg[1] = Wih; Wg[2] = Woh; Wg[3] = Wch;
        } else {
            int jj = j0 - KORD * HH;
            k = jj >> 7; fb = jj & 127; F = II;
            abase = Tx + ((size_t)k * NN) * II + fb; astr = II;
            Wg[0] = Wfx; Wg[1] = Wix; Wg[2] = Wox; Wg[3] = Wcx;
        }
        // A tile: 64 rows x 32 cols
#pragma unroll
        for (int l = 0; l < 8; ++l) {
            int li = t + l * 256;
            int kk = li & 31, m = li >> 5;
            As[kk][m] = abase[(size_t)(n0 + m) * astr + kk];
        }
        // B tiles: 4 gates x 64 hcols x 32
#pragma unroll
        for (int g = 0; g < 4; ++g) {
            const float* wb = Wg[g] + ((size_t)k * HH) * F + fb;
#pragma unroll
            for (int l = 0; l < 8; ++l) {
                int li = t + l * 256;
                int kk = li & 31, hh = li >> 5;
                Bs[g][kk][hh] = wb[(size_t)(h0 + hh) * F + kk];
            }
        }
        __syncthreads();
#pragma unroll 8
        for (int kk = 0; kk < BK; ++kk) {
            float a[4], b[4][4];
#pragma unroll
            for (int i = 0; i < 4; ++i) a[i] = As[kk][ty * 4 + i];
#pragma unroll
            for (int g = 0; g < 4; ++g)
#pragma unroll
                for (int j = 0; j < 4; ++j) b[g][j] = Bs[g][kk][tx * 4 + j];
#pragma unroll
            for (int g = 0; g < 4; ++g)
#pragma unroll
                for (int i = 0; i < 4; ++i)
#pragma unroll
                    for (int j = 0; j < 4; ++j) acc[g][i][j] += a[i] * b[g][j];
        }
        __syncthreads();
    }

    // LSTM elementwise epilogue
#pragma unroll
    for (int i = 0; i < 4; ++i) {
        int n = n0 + ty * 4 + i;
#pragma unroll
        for (int j = 0; j < 4; ++j) {
            int h = h0 + tx * 4 + j;
            size_t idx = (size_t)n * HH + h;
            float fg = sigmoidf_(acc[0][i][j] + bf[idx]);
            float ig = sigmoidf_(acc[1][i][j] + bi[idx]);
            float og = sigmoidf_(acc[2][i][j] + bo[idx]);
            float cg = tanhf(acc[3][i][j] + bc[idx]);
            float cn = ig * cg + fg * cin[idx];
            float hn = og * tanhf(cn);
            out[idx] = hn;
            out[(size_t)NN * HH + idx] = cn;
        }
    }
}

// ---------------- launch ----------------
extern "C" void kernel_launch(void* const* d_in, const int* in_sizes, int n_in,
                              void* d_out, int out_size, void* d_ws, size_t ws_size,
                              hipStream_t stream) {
    const float* x   = (const float*)d_in[0];
    const float* h   = (const float*)d_in[1];
    const float* c   = (const float*)d_in[2];
    const float* lap = (const float*)d_in[3];
    const int*   pos = (const int*)d_in[4];
    const float* Wfh = (const float*)d_in[5];
    const float* Wfx = (const float*)d_in[6];
    const float* bf  = (const float*)d_in[7];
    const float* Wih = (const float*)d_in[8];
    const float* Wix = (const float*)d_in[9];
    const float* bi  = (const float*)d_in[10];
    const float* Woh = (const float*)d_in[11];
    const float* Wox = (const float*)d_in[12];
    const float* bo  = (const float*)d_in[13];
    const float* Wch = (const float*)d_in[14];
    const float* Wcx = (const float*)d_in[15];
    const float* bc  = (const float*)d_in[16];
    float* out = (float*)d_out;

    uint8_t* ws = (uint8_t*)d_ws;
    size_t off = 0;
    auto take = [&](size_t bytes) -> void* {
        void* p = ws + off;
        off += (bytes + 255) & ~(size_t)255;
        return p;
    };
    uint32_t* hkey = (uint32_t*)take((size_t)TBL * 4);
    uint32_t* hidx = (uint32_t*)take((size_t)TBL * 4);
    int*      flag = (int*)take(4);
    uint32_t* rcnt = (uint32_t*)take((size_t)NN * 4);
    uint32_t* rptr = (uint32_t*)take((size_t)(NN + 1) * 4);
    uint32_t* curs = (uint32_t*)take((size_t)NN * 4);
    float*    vdd  = (float*)take((size_t)EE * 4);
    uint32_t* ccol = (uint32_t*)take((size_t)EE * 4);
    float*    cval = (float*)take((size_t)EE * 4);
    float*    Th   = (float*)take((size_t)KORD * NN * HH * 4);  // 33.5 MB
    float*    Tx   = (float*)take((size_t)KORD * NN * II * 4);  // 16.8 MB
    // total ws use ~62 MB

    // T0 copies (contiguous [K][N][F] storage for the GEMM)
    hipMemcpyAsync(Th, h, (size_t)NN * HH * 4, hipMemcpyDeviceToDevice, stream);
    hipMemcpyAsync(Tx, x, (size_t)NN * II * 4, hipMemcpyDeviceToDevice, stream);

    init_ws<<<TBL / 256, 256, 0, stream>>>(hkey, hidx, rcnt);
    detect_layout<<<1, 64, 0, stream>>>(pos, flag);
    build_hash<<<EE / 256, 256, 0, stream>>>(pos, flag, hkey, hidx);
    dedup_vals<<<EE / 256, 256, 0, stream>>>(pos, flag, lap, hkey, hidx, vdd);
    count_rows<<<EE / 256, 256, 0, stream>>>(pos, flag, rcnt);
    scan_rows<<<1, 1024, 0, stream>>>(rcnt, rptr, curs);
    scatter_csr<<<EE / 256, 256, 0, stream>>>(pos, flag, vdd, curs, ccol, cval);

    float* Th0 = Th;
    float* Th1 = Th + (size_t)NN * HH;
    float* Th2 = Th1 + (size_t)NN * HH;
    float* Th3 = Th2 + (size_t)NN * HH;
    float* Tx0 = Tx;
    float* Tx1 = Tx + (size_t)NN * II;
    float* Tx2 = Tx1 + (size_t)NN * II;
    float* Tx3 = Tx2 + (size_t)NN * II;

    // T1 = L@T0 ; T2 = 2 L@T1 - T0 ; T3 = 2 L@T2 - T1
    spmv_cheb<HH><<<NN, HH, 0, stream>>>(rptr, ccol, cval, h,   h,   Th1, 1.0f,  0.0f);
    spmv_cheb<HH><<<NN, HH, 0, stream>>>(rptr, ccol, cval, Th1, Th0, Th2, 2.0f, -1.0f);
    spmv_cheb<HH><<<NN, HH, 0, stream>>>(rptr, ccol, cval, Th2, Th1, Th3, 2.0f, -1.0f);
    spmv_cheb<II><<<NN, II, 0, stream>>>(rptr, ccol, cval, x,   x,   Tx1, 1.0f,  0.0f);
    spmv_cheb<II><<<NN, II, 0, stream>>>(rptr, ccol, cval, Tx1, Tx0, Tx2, 2.0f, -1.0f);
    spmv_cheb<II><<<NN, II, 0, stream>>>(rptr, ccol, cval, Tx2, Tx1, Tx3, 2.0f, -1.0f);

    dim3 gg(HH / BN, NN / BM);
    gemm_lstm<<<gg, 256, 0, stream>>>(Th, Tx, Wfh, Wfx, Wih, Wix, Woh, Wox, Wch, Wcx,
                                      bf, bi, bo, bc, c, out);
}

// Round 2
// 399.806 us; speedup vs baseline: 2.6762x; 2.6762x over previous
//
#include <hip/hip_runtime.h>
#include <hip/hip_bf16.h>
#include <cstdint>

// Problem constants (fixed by reference)
#define NN 8192
#define HH 256
#define II 128
#define KORD 4
#define EE 262144
#define KW 1536          // GEMM K = 4*(256+128)
#define MW 1024          // GEMM output cols = 4 gates * 256
#define TBL (1u << 20)   // hash table slots (load factor 0.25)

typedef __attribute__((ext_vector_type(8))) short bf16x8;
typedef __attribute__((ext_vector_type(4))) float f32x4;

// ---------------- pos layout handling (int32 vs int64 words) ----------------
__device__ __forceinline__ void read_pos(const int* __restrict__ pos, int flag,
                                         int e, int& r, int& c) {
    if (flag) { r = pos[4 * e]; c = pos[4 * e + 2]; }   // int64 little-endian
    else      { r = pos[2 * e]; c = pos[2 * e + 1]; }   // int32
}

__global__ void detect_layout(const int* __restrict__ pos, int* __restrict__ flag) {
    if (threadIdx.x == 0 && blockIdx.x == 0) {
        int f = 1;
        for (int i = 0; i < 128; ++i) {
            if (pos[2 * i + 1] != 0) { f = 0; break; }
        }
        *flag = f;
    }
}

// ---------------- init ----------------
__global__ void init_ws(uint32_t* __restrict__ hkey, uint32_t* __restrict__ hidx,
                        uint32_t* __restrict__ rcnt) {
    int i = blockIdx.x * blockDim.x + threadIdx.x;
    if (i < (int)TBL) { hkey[i] = 0xFFFFFFFFu; hidx[i] = 0u; }
    if (i < NN) rcnt[i] = 0u;
}

__device__ __forceinline__ uint32_t hash_key(uint32_t key) {
    return (key * 2654435761u) >> 6 & (TBL - 1u);
}

// ---------------- dedupe: last write wins ----------------
__global__ void build_hash(const int* __restrict__ pos, const int* __restrict__ flagp,
                           uint32_t* __restrict__ hkey, uint32_t* __restrict__ hidx) {
    int e = blockIdx.x * blockDim.x + threadIdx.x;
    if (e >= EE) return;
    int flag = *flagp;
    int r, c; read_pos(pos, flag, e, r, c);
    uint32_t key = (uint32_t)r * (uint32_t)NN + (uint32_t)c;
    uint32_t slot = hash_key(key);
    for (;;) {
        uint32_t prev = atomicCAS(&hkey[slot], 0xFFFFFFFFu, key);
        if (prev == 0xFFFFFFFFu || prev == key) {
            atomicMax(&hidx[slot], (uint32_t)(e + 1));
            break;
        }
        slot = (slot + 1u) & (TBL - 1u);
    }
}

// ---------------- CSR build ----------------
__global__ void count_rows(const int* __restrict__ pos, const int* __restrict__ flagp,
                           uint32_t* __restrict__ rcnt) {
    int e = blockIdx.x * blockDim.x + threadIdx.x;
    if (e >= EE) return;
    int flag = *flagp;
    int r, c; read_pos(pos, flag, e, r, c);
    atomicAdd(&rcnt[r], 1u);
}

__global__ __launch_bounds__(1024) void scan_rows(const uint32_t* __restrict__ cnt,
                                                  uint32_t* __restrict__ rptr,
                                                  uint32_t* __restrict__ curs) {
    __shared__ uint32_t part[1024];
    int t = threadIdx.x;
    uint32_t loc[8];
    uint32_t s = 0;
#pragma unroll
    for (int i = 0; i < 8; ++i) { loc[i] = s; s += cnt[t * 8 + i]; }
    part[t] = s;
    __syncthreads();
    for (int o = 1; o < 1024; o <<= 1) {
        uint32_t xv = part[t];
        uint32_t yv = (t >= o) ? part[t - o] : 0u;
        __syncthreads();
        part[t] = xv + yv;
        __syncthreads();
    }
    uint32_t base = part[t] - s;  // exclusive prefix for this thread
#pragma unroll
    for (int i = 0; i < 8; ++i) {
        uint32_t v = base + loc[i];
        rptr[t * 8 + i] = v;
        curs[t * 8 + i] = v;
    }
    if (t == 1023) rptr[NN] = part[1023];
}

// scatter with fused dedup (last-write-wins via hash winner index)
__global__ void scatter_csr(const int* __restrict__ pos, const int* __restrict__ flagp,
                            const float* __restrict__ lap,
                            const uint32_t* __restrict__ hkey, const uint32_t* __restrict__ hidx,
                            uint32_t* __restrict__ curs,
                            uint32_t* __restrict__ ccol, float* __restrict__ cval) {
    int e = blockIdx.x * blockDim.x + threadIdx.x;
    if (e >= EE) return;
    int flag = *flagp;
    int r, c; read_pos(pos, flag, e, r, c);
    uint32_t key = (uint32_t)r * (uint32_t)NN + (uint32_t)c;
    uint32_t slot = hash_key(key);
    while (hkey[slot] != key) slot = (slot + 1u) & (TBL - 1u);
    float v = (hidx[slot] == (uint32_t)(e + 1)) ? lap[e] : 0.0f;
    uint32_t dst = atomicAdd(&curs[r], 1u);
    ccol[dst] = (uint32_t)c;
    cval[dst] = v;
}

// ---------------- SpMV with fused Chebyshev recurrence + bf16 emit ----------
// Y[r,:] = a * (L @ X)[r,:] + b * Prev[r,:] ; also A[r, colbase+t] = bf16(Y)
template <int F>
__global__ void spmv_cheb(const uint32_t* __restrict__ rptr,
                          const uint32_t* __restrict__ ccol,
                          const float* __restrict__ cval,
                          const float* __restrict__ X,
                          const float* __restrict__ Prev,
                          float* __restrict__ Y,
                          __hip_bfloat16* __restrict__ Abf, int colbase,
                          float a, float b) {
    int r = blockIdx.x;
    int t = threadIdx.x;
    uint32_t s = rptr[r], e = rptr[r + 1];
    float acc = 0.0f;
    for (uint32_t i = s; i < e; ++i) {
        float v = cval[i];
        uint32_t c = ccol[i];
        acc += v * X[(size_t)c * F + t];
    }
    float o = a * acc;
    if (b != 0.0f) o += b * Prev[(size_t)r * F + t];
    Y[(size_t)r * F + t] = o;
    Abf[(size_t)r * KW + colbase + t] = __float2bfloat16(o);
}

// ---------------- pack kernels ----------------
// A level-0 columns: cols [0,256) = h, cols [1024,1152) = x
__global__ void pack_A0(const float* __restrict__ h, const float* __restrict__ x,
                        __hip_bfloat16* __restrict__ A) {
    int idx = blockIdx.x * blockDim.x + threadIdx.x;  // over NN*384
    if (idx >= NN * 384) return;
    int n = idx / 384, q = idx - n * 384;
    float v; int col;
    if (q < 256) { v = h[(size_t)n * HH + q]; col = q; }
    else         { v = x[(size_t)n * II + (q - 256)]; col = 1024 + (q - 256); }
    A[(size_t)n * KW + col] = __float2bfloat16(v);
}

// B matrix [1024][1536]: row m = g*256+h ; col j<1024: Th block (k=j>>8,f=j&255)
// col j>=1024: Tx block (k=(j-1024)>>7, f=(j-1024)&127)
__global__ void pack_B(const float* __restrict__ Wfh, const float* __restrict__ Wih,
                       const float* __restrict__ Woh, const float* __restrict__ Wch,
                       const float* __restrict__ Wfx, const float* __restrict__ Wix,
                       const float* __restrict__ Wox, const float* __restrict__ Wcx,
                       __hip_bfloat16* __restrict__ Bm) {
    int idx = blockIdx.x * blockDim.x + threadIdx.x;  // over MW*KW
    if (idx >= MW * KW) return;
    int m = idx / KW, j = idx - m * KW;
    int g = m >> 8, hh = m & 255;
    const float* Wh = (g == 0) ? Wfh : (g == 1) ? Wih : (g == 2) ? Woh : Wch;
    const float* Wx = (g == 0) ? Wfx : (g == 1) ? Wix : (g == 2) ? Wox : Wcx;
    float v;
    if (j < 1024) { int k = j >> 8, f = j & 255; v = Wh[((size_t)k * HH + hh) * HH + f]; }
    else { int jj = j - 1024; int k = jj >> 7, f = jj & 127; v = Wx[((size_t)k * HH + hh) * II + f]; }
    Bm[idx] = __float2bfloat16(v);
}

// ---------------- bf16 MFMA GEMM (m97 structure: 128x128 tile, BK=32) -------
__device__ __forceinline__ void gload_lds16(const void* g, void* l) {
    __builtin_amdgcn_global_load_lds(
        (const __attribute__((address_space(1))) void*)g,
        (__attribute__((address_space(3))) void*)l, 16, 0, 0);
}

__global__ __launch_bounds__(256) void gemm_mfma(
    const __hip_bfloat16* __restrict__ A,   // [NN][KW]
    const __hip_bfloat16* __restrict__ B,   // [MW][KW]
    float* __restrict__ C) {                // [NN][MW]
    __shared__ short Alds[128 * 32];
    __shared__ short Blds[128 * 32];
    int m0 = blockIdx.x * 128;   // output col tile
    int n0 = blockIdx.y * 128;   // output row tile
    int t = threadIdx.x;
    int w = t >> 6, l = t & 63;
    int wr = w >> 1, wc = w & 1;
    int lrow = l & 15, lk = (l >> 4) * 8;

    f32x4 acc[4][4];
#pragma unroll
    for (int i = 0; i < 4; ++i)
#pragma unroll
        for (int j = 0; j < 4; ++j) acc[i][j] = (f32x4)0.0f;

    for (int k0 = 0; k0 < KW; k0 += 32) {
        // stage A,B tiles (128x32 bf16 each) via direct global->LDS, 16B/lane
#pragma unroll
        for (int s = 0; s < 2; ++s) {
            int e = (s * 256 + t) * 8;       // bf16 element index in tile
            int row = e >> 5, kk = e & 31;
            gload_lds16(&A[(size_t)(n0 + row) * KW + k0 + kk], &Alds[e]);
            gload_lds16(&B[(size_t)(m0 + row) * KW + k0 + kk], &Blds[e]);
        }
        __syncthreads();
        bf16x8 af[4], bfr[4];
#pragma unroll
        for (int i = 0; i < 4; ++i)
            af[i] = *(const bf16x8*)&Alds[(wr * 64 + i * 16 + lrow) * 32 + lk];
#pragma unroll
        for (int j = 0; j < 4; ++j)
            bfr[j] = *(const bf16x8*)&Blds[(wc * 64 + j * 16 + lrow) * 32 + lk];
#pragma unroll
        for (int i = 0; i < 4; ++i)
#pragma unroll
            for (int j = 0; j < 4; ++j)
                acc[i][j] = __builtin_amdgcn_mfma_f32_16x16x32_bf16(af[i], bfr[j], acc[i][j], 0, 0, 0);
        __syncthreads();
    }

    int r4 = (l >> 4) * 4;
#pragma unroll
    for (int i = 0; i < 4; ++i)
#pragma unroll
        for (int j = 0; j < 4; ++j)
#pragma unroll
            for (int r = 0; r < 4; ++r) {
                int row = n0 + wr * 64 + i * 16 + r4 + r;
                int col = m0 + wc * 64 + j * 16 + lrow;
                C[(size_t)row * MW + col] = acc[i][j][r];
            }
}

// ---------------- LSTM elementwise epilogue ----------------
__device__ __forceinline__ float sigmoidf_(float x) { return 1.0f / (1.0f + expf(-x)); }

__global__ __launch_bounds__(256) void lstm_ew(
    const float* __restrict__ C,            // [NN][MW] preacts, gate g at col g*256+h
    const float* __restrict__ bf, const float* __restrict__ bi,
    const float* __restrict__ bo, const float* __restrict__ bc,
    const float* __restrict__ cin, float* __restrict__ out) {
    int i = blockIdx.x * blockDim.x + threadIdx.x;  // over NN*HH/4
    if (i >= NN * HH / 4) return;
    int n = i >> 6;           // HH/4 = 64 float4 per row
    int h4 = (i & 63) * 4;
    size_t cb = (size_t)n * MW;
    size_t hb = (size_t)n * HH + h4;
    float4 pf = *(const float4*)&C[cb + 0 * HH + h4];
    float4 pi = *(const float4*)&C[cb + 1 * HH + h4];
    float4 po = *(const float4*)&C[cb + 2 * HH + h4];
    float4 pc = *(const float4*)&C[cb + 3 * HH + h4];
    float4 vbf = *(const float4*)&bf[hb];
    float4 vbi = *(const float4*)&bi[hb];
    float4 vbo = *(const float4*)&bo[hb];
    float4 vbc = *(const float4*)&bc[hb];
    float4 vc  = *(const float4*)&cin[hb];
    float4 hn, cn;
    {
        float fg = sigmoidf_(pf.x + vbf.x), ig = sigmoidf_(pi.x + vbi.x);
        float og = sigmoidf_(po.x + vbo.x), cg = tanhf(pc.x + vbc.x);
        cn.x = ig * cg + fg * vc.x; hn.x = og * tanhf(cn.x);
    }
    {
        float fg = sigmoidf_(pf.y + vbf.y), ig = sigmoidf_(pi.y + vbi.y);
        float og = sigmoidf_(po.y + vbo.y), cg = tanhf(pc.y + vbc.y);
        cn.y = ig * cg + fg * vc.y; hn.y = og * tanhf(cn.y);
    }
    {
        float fg = sigmoidf_(pf.z + vbf.z), ig = sigmoidf_(pi.z + vbi.z);
        float og = sigmoidf_(po.z + vbo.z), cg = tanhf(pc.z + vbc.z);
        cn.z = ig * cg + fg * vc.z; hn.z = og * tanhf(cn.z);
    }
    {
        float fg = sigmoidf_(pf.w + vbf.w), ig = sigmoidf_(pi.w + vbi.w);
        float og = sigmoidf_(po.w + vbo.w), cg = tanhf(pc.w + vbc.w);
        cn.w = ig * cg + fg * vc.w; hn.w = og * tanhf(cn.w);
    }
    *(float4*)&out[hb] = hn;
    *(float4*)&out[(size_t)NN * HH + hb] = cn;
}

// ---------------- launch ----------------
extern "C" void kernel_launch(void* const* d_in, const int* in_sizes, int n_in,
                              void* d_out, int out_size, void* d_ws, size_t ws_size,
                              hipStream_t stream) {
    const float* x   = (const float*)d_in[0];
    const float* h   = (const float*)d_in[1];
    const float* c   = (const float*)d_in[2];
    const float* lap = (const float*)d_in[3];
    const int*   pos = (const int*)d_in[4];
    const float* Wfh = (const float*)d_in[5];
    const float* Wfx = (const float*)d_in[6];
    const float* bf  = (const float*)d_in[7];
    const float* Wih = (const float*)d_in[8];
    const float* Wix = (const float*)d_in[9];
    const float* bi  = (const float*)d_in[10];
    const float* Woh = (const float*)d_in[11];
    const float* Wox = (const float*)d_in[12];
    const float* bo  = (const float*)d_in[13];
    const float* Wch = (const float*)d_in[14];
    const float* Wcx = (const float*)d_in[15];
    const float* bc  = (const float*)d_in[16];
    float* out = (float*)d_out;

    uint8_t* ws = (uint8_t*)d_ws;
    size_t off = 0;
    auto take = [&](size_t bytes) -> void* {
        void* p = ws + off;
        off += (bytes + 255) & ~(size_t)255;
        return p;
    };
    uint32_t* hkey = (uint32_t*)take((size_t)TBL * 4);
    uint32_t* hidx = (uint32_t*)take((size_t)TBL * 4);
    int*      flag = (int*)take(4);
    uint32_t* rcnt = (uint32_t*)take((size_t)NN * 4);
    uint32_t* rptr = (uint32_t*)take((size_t)(NN + 1) * 4);
    uint32_t* curs = (uint32_t*)take((size_t)NN * 4);
    uint32_t* ccol = (uint32_t*)take((size_t)EE * 4);
    float*    cval = (float*)take((size_t)EE * 4);
    float*    Thf  = (float*)take((size_t)3 * NN * HH * 4);   // levels 1..3
    float*    Txf  = (float*)take((size_t)3 * NN * II * 4);   // levels 1..3
    __hip_bfloat16* Amat = (__hip_bfloat16*)take((size_t)NN * KW * 2);  // 25.2 MB
    __hip_bfloat16* Bmat = (__hip_bfloat16*)take((size_t)MW * KW * 2);  // 3.1 MB
    float*    Cpre = (float*)take((size_t)NN * MW * 4);       // 33.5 MB
    // total ws use ~110 MB

    init_ws<<<TBL / 256, 256, 0, stream>>>(hkey, hidx, rcnt);
    detect_layout<<<1, 64, 0, stream>>>(pos, flag);
    build_hash<<<EE / 256, 256, 0, stream>>>(pos, flag, hkey, hidx);
    count_rows<<<EE / 256, 256, 0, stream>>>(pos, flag, rcnt);
    scan_rows<<<1, 1024, 0, stream>>>(rcnt, rptr, curs);
    scatter_csr<<<EE / 256, 256, 0, stream>>>(pos, flag, lap, hkey, hidx, curs, ccol, cval);

    pack_A0<<<(NN * 384 + 255) / 256, 256, 0, stream>>>(h, x, Amat);
    pack_B<<<(MW * KW + 255) / 256, 256, 0, stream>>>(Wfh, Wih, Woh, Wch,
                                                      Wfx, Wix, Wox, Wcx, Bmat);

    float* Th1 = Thf;
    float* Th2 = Th1 + (size_t)NN * HH;
    float* Th3 = Th2 + (size_t)NN * HH;
    float* Tx1 = Txf;
    float* Tx2 = Tx1 + (size_t)NN * II;
    float* Tx3 = Tx2 + (size_t)NN * II;

    // T1 = L@T0 ; T2 = 2 L@T1 - T0 ; T3 = 2 L@T2 - T1  (levels into A cols)
    spmv_cheb<HH><<<NN, HH, 0, stream>>>(rptr, ccol, cval, h,   h,   Th1, Amat, 256,  1.0f,  0.0f);
    spmv_cheb<HH><<<NN, HH, 0, stream>>>(rptr, ccol, cval, Th1, h,   Th2, Amat, 512,  2.0f, -1.0f);
    spmv_cheb<HH><<<NN, HH, 0, stream>>>(rptr, ccol, cval, Th2, Th1, Th3, Amat, 768,  2.0f, -1.0f);
    spmv_cheb<II><<<NN, II, 0, stream>>>(rptr, ccol, cval, x,   x,   Tx1, Amat, 1152, 1.0f,  0.0f);
    spmv_cheb<II><<<NN, II, 0, stream>>>(rptr, ccol, cval, Tx1, x,   Tx2, Amat, 1280, 2.0f, -1.0f);
    spmv_cheb<II><<<NN, II, 0, stream>>>(rptr, ccol, cval, Tx2, Tx1, Tx3, Amat, 1408, 2.0f, -1.0f);

    dim3 gg(MW / 128, NN / 128);
    gemm_mfma<<<gg, 256, 0, stream>>>(Amat, Bmat, Cpre);

    lstm_ew<<<(NN * HH / 4 + 255) / 256, 256, 0, stream>>>(Cpre, bf, bi, bo, bc, c, out);
}

// Round 3
// 268.915 us; speedup vs baseline: 3.9788x; 1.4867x over previous
//
#include <hip/hip_runtime.h>
#include <hip/hip_bf16.h>
#include <cstdint>

// Problem constants (fixed by reference)
#define NN 8192
#define HH 256
#define II 128
#define KORD 4
#define EE 262144
#define KW 1536          // GEMM K = 4*(256+128)
#define MW 1024          // GEMM output cols = 4 gates * 256
#define TBL (1u << 20)   // hash table slots (load factor 0.25)

typedef __attribute__((ext_vector_type(8))) short bf16x8;
typedef __attribute__((ext_vector_type(4))) float f32x4;

// ---------------- pos layout handling (int32 vs int64 words) ----------------
__device__ __forceinline__ void read_pos(const int* __restrict__ pos, int flag,
                                         int e, int& r, int& c) {
    if (flag) { r = pos[4 * e]; c = pos[4 * e + 2]; }   // int64 little-endian
    else      { r = pos[2 * e]; c = pos[2 * e + 1]; }   // int32
}

// ---------------- init (+ layout detect in block 0) ----------------
__global__ void init_ws(uint32_t* __restrict__ hkey, uint32_t* __restrict__ hidx,
                        uint32_t* __restrict__ rcnt,
                        const int* __restrict__ pos, int* __restrict__ flag) {
    int i = blockIdx.x * blockDim.x + threadIdx.x;
    if (i < (int)TBL) { hkey[i] = 0xFFFFFFFFu; hidx[i] = 0u; }
    if (i < NN) rcnt[i] = 0u;
    if (i == 0) {
        int f = 1;
        for (int k = 0; k < 128; ++k) {
            if (pos[2 * k + 1] != 0) { f = 0; break; }
        }
        *flag = f;
    }
}

__device__ __forceinline__ uint32_t hash_key(uint32_t key) {
    return (key * 2654435761u) >> 6 & (TBL - 1u);
}

// ---------------- dedupe (last write wins) + row count ----------------
__global__ void build_hash(const int* __restrict__ pos, const int* __restrict__ flagp,
                           uint32_t* __restrict__ hkey, uint32_t* __restrict__ hidx,
                           uint32_t* __restrict__ rcnt) {
    int e = blockIdx.x * blockDim.x + threadIdx.x;
    if (e >= EE) return;
    int flag = *flagp;
    int r, c; read_pos(pos, flag, e, r, c);
    uint32_t key = (uint32_t)r * (uint32_t)NN + (uint32_t)c;
    uint32_t slot = hash_key(key);
    for (;;) {
        uint32_t prev = atomicCAS(&hkey[slot], 0xFFFFFFFFu, key);
        if (prev == 0xFFFFFFFFu || prev == key) {
            atomicMax(&hidx[slot], (uint32_t)(e + 1));
            break;
        }
        slot = (slot + 1u) & (TBL - 1u);
    }
    atomicAdd(&rcnt[r], 1u);
}

__global__ __launch_bounds__(1024) void scan_rows(const uint32_t* __restrict__ cnt,
                                                  uint32_t* __restrict__ rptr,
                                                  uint32_t* __restrict__ curs) {
    __shared__ uint32_t part[1024];
    int t = threadIdx.x;
    uint32_t loc[8];
    uint32_t s = 0;
#pragma unroll
    for (int i = 0; i < 8; ++i) { loc[i] = s; s += cnt[t * 8 + i]; }
    part[t] = s;
    __syncthreads();
    for (int o = 1; o < 1024; o <<= 1) {
        uint32_t xv = part[t];
        uint32_t yv = (t >= o) ? part[t - o] : 0u;
        __syncthreads();
        part[t] = xv + yv;
        __syncthreads();
    }
    uint32_t base = part[t] - s;  // exclusive prefix for this thread
#pragma unroll
    for (int i = 0; i < 8; ++i) {
        uint32_t v = base + loc[i];
        rptr[t * 8 + i] = v;
        curs[t * 8 + i] = v;
    }
    if (t == 1023) rptr[NN] = part[1023];
}

// scatter with fused dedup (last-write-wins via hash winner index)
__global__ void scatter_csr(const int* __restrict__ pos, const int* __restrict__ flagp,
                            const float* __restrict__ lap,
                            const uint32_t* __restrict__ hkey, const uint32_t* __restrict__ hidx,
                            uint32_t* __restrict__ curs,
                            uint32_t* __restrict__ ccol, float* __restrict__ cval) {
    int e = blockIdx.x * blockDim.x + threadIdx.x;
    if (e >= EE) return;
    int flag = *flagp;
    int r, c; read_pos(pos, flag, e, r, c);
    uint32_t key = (uint32_t)r * (uint32_t)NN + (uint32_t)c;
    uint32_t slot = hash_key(key);
    while (hkey[slot] != key) slot = (slot + 1u) & (TBL - 1u);
    float v = (hidx[slot] == (uint32_t)(e + 1)) ? lap[e] : 0.0f;
    uint32_t dst = atomicAdd(&curs[r], 1u);
    ccol[dst] = (uint32_t)c;
    cval[dst] = v;
}

// ---------------- SpMV: float4 gather, unroll-4, fused recurrence + bf16 ----
template <int F4>
__device__ __forceinline__ void spmv_row(
    const uint32_t* __restrict__ rptr, const uint32_t* __restrict__ ccol,
    const float* __restrict__ cval,
    const float4* __restrict__ X4, const float4* __restrict__ P4,
    float4* __restrict__ Y4, __hip_bfloat16* __restrict__ Abf, int colbase,
    float a, float b, int r, int lane) {
    uint32_t s = rptr[r], e = rptr[r + 1];
    float ax = 0.f, ay = 0.f, az = 0.f, aw = 0.f;
    uint32_t i = s;
    for (; i + 4 <= e; i += 4) {
        uint32_t c0 = ccol[i + 0], c1 = ccol[i + 1], c2 = ccol[i + 2], c3 = ccol[i + 3];
        float v0 = cval[i + 0], v1 = cval[i + 1], v2 = cval[i + 2], v3 = cval[i + 3];
        float4 x0 = X4[(size_t)c0 * F4 + lane];
        float4 x1 = X4[(size_t)c1 * F4 + lane];
        float4 x2 = X4[(size_t)c2 * F4 + lane];
        float4 x3 = X4[(size_t)c3 * F4 + lane];
        ax += v0 * x0.x + v1 * x1.x + v2 * x2.x + v3 * x3.x;
        ay += v0 * x0.y + v1 * x1.y + v2 * x2.y + v3 * x3.y;
        az += v0 * x0.z + v1 * x1.z + v2 * x2.z + v3 * x3.z;
        aw += v0 * x0.w + v1 * x1.w + v2 * x2.w + v3 * x3.w;
    }
    for (; i < e; ++i) {
        uint32_t c0 = ccol[i];
        float v0 = cval[i];
        float4 x0 = X4[(size_t)c0 * F4 + lane];
        ax += v0 * x0.x; ay += v0 * x0.y; az += v0 * x0.z; aw += v0 * x0.w;
    }
    float4 o;
    o.x = a * ax; o.y = a * ay; o.z = a * az; o.w = a * aw;
    if (b != 0.0f) {
        float4 p = P4[(size_t)r * F4 + lane];
        o.x += b * p.x; o.y += b * p.y; o.z += b * p.z; o.w += b * p.w;
    }
    Y4[(size_t)r * F4 + lane] = o;
    __hip_bfloat16 b0 = __float2bfloat16(o.x), b1 = __float2bfloat16(o.y);
    __hip_bfloat16 b2 = __float2bfloat16(o.z), b3 = __float2bfloat16(o.w);
    ushort4 pk;
    pk.x = *(unsigned short*)&b0; pk.y = *(unsigned short*)&b1;
    pk.z = *(unsigned short*)&b2; pk.w = *(unsigned short*)&b3;
    *(ushort4*)&Abf[(size_t)r * KW + colbase + lane * 4] = pk;
}

// one launch = one Chebyshev level for BOTH h (F=256) and x (F=128)
__global__ __launch_bounds__(256) void spmv_cheb_dual(
    const uint32_t* __restrict__ rptr, const uint32_t* __restrict__ ccol,
    const float* __restrict__ cval,
    const float4* __restrict__ Xh, const float4* __restrict__ Ph,
    float4* __restrict__ Yh, int cbh,
    const float4* __restrict__ Xx, const float4* __restrict__ Px,
    float4* __restrict__ Yx, int cbx,
    __hip_bfloat16* __restrict__ Abf, float a, float b) {
    int bid = blockIdx.x, t = threadIdx.x;
    if (bid < NN / 4) {
        int r = bid * 4 + (t >> 6), lane = t & 63;
        spmv_row<64>(rptr, ccol, cval, Xh, Ph, Yh, Abf, cbh, a, b, r, lane);
    } else {
        int r = (bid - NN / 4) * 8 + (t >> 5), lane = t & 31;
        spmv_row<32>(rptr, ccol, cval, Xx, Px, Yx, Abf, cbx, a, b, r, lane);
    }
}

// ---------------- pack kernels ----------------
// A level-0 columns: cols [0,256) = h, cols [1024,1152) = x
__global__ void pack_A0(const float* __restrict__ h, const float* __restrict__ x,
                        __hip_bfloat16* __restrict__ A) {
    int idx = blockIdx.x * blockDim.x + threadIdx.x;  // over NN*384
    if (idx >= NN * 384) return;
    int n = idx / 384, q = idx - n * 384;
    float v; int col;
    if (q < 256) { v = h[(size_t)n * HH + q]; col = q; }
    else         { v = x[(size_t)n * II + (q - 256)]; col = 1024 + (q - 256); }
    A[(size_t)n * KW + col] = __float2bfloat16(v);
}

// B matrix [1024][1536]: row m = g*256+h
__global__ void pack_B(const float* __restrict__ Wfh, const float* __restrict__ Wih,
                       const float* __restrict__ Woh, const float* __restrict__ Wch,
                       const float* __restrict__ Wfx, const float* __restrict__ Wix,
                       const float* __restrict__ Wox, const float* __restrict__ Wcx,
                       __hip_bfloat16* __restrict__ Bm) {
    int idx = blockIdx.x * blockDim.x + threadIdx.x;  // over MW*KW
    if (idx >= MW * KW) return;
    int m = idx / KW, j = idx - m * KW;
    int g = m >> 8, hh = m & 255;
    const float* Wh = (g == 0) ? Wfh : (g == 1) ? Wih : (g == 2) ? Woh : Wch;
    const float* Wx = (g == 0) ? Wfx : (g == 1) ? Wix : (g == 2) ? Wox : Wcx;
    float v;
    if (j < 1024) { int k = j >> 8, f = j & 255; v = Wh[((size_t)k * HH + hh) * HH + f]; }
    else { int jj = j - 1024; int k = jj >> 7, f = jj & 127; v = Wx[((size_t)k * HH + hh) * II + f]; }
    Bm[idx] = __float2bfloat16(v);
}

// ---------------- bf16 MFMA GEMM (m97 structure: 128x128 tile, BK=32) -------
__device__ __forceinline__ void gload_lds16(const void* g, void* l) {
    __builtin_amdgcn_global_load_lds(
        (const __attribute__((address_space(1))) void*)g,
        (__attribute__((address_space(3))) void*)l, 16, 0, 0);
}

__global__ __launch_bounds__(256) void gemm_mfma(
    const __hip_bfloat16* __restrict__ A,   // [NN][KW]
    const __hip_bfloat16* __restrict__ B,   // [MW][KW]
    float* __restrict__ C) {                // [NN][MW]
    __shared__ short Alds[128 * 32];
    __shared__ short Blds[128 * 32];
    int m0 = blockIdx.x * 128;   // output col tile
    int n0 = blockIdx.y * 128;   // output row tile
    int t = threadIdx.x;
    int w = t >> 6, l = t & 63;
    int wr = w >> 1, wc = w & 1;
    int lrow = l & 15, lk = (l >> 4) * 8;

    f32x4 acc[4][4];
#pragma unroll
    for (int i = 0; i < 4; ++i)
#pragma unroll
        for (int j = 0; j < 4; ++j) acc[i][j] = (f32x4)0.0f;

    for (int k0 = 0; k0 < KW; k0 += 32) {
#pragma unroll
        for (int s = 0; s < 2; ++s) {
            int e = (s * 256 + t) * 8;       // bf16 element index in tile
            int row = e >> 5, kk = e & 31;
            gload_lds16(&A[(size_t)(n0 + row) * KW + k0 + kk], &Alds[e]);
            gload_lds16(&B[(size_t)(m0 + row) * KW + k0 + kk], &Blds[e]);
        }
        __syncthreads();
        bf16x8 af[4], bfr[4];
#pragma unroll
        for (int i = 0; i < 4; ++i)
            af[i] = *(const bf16x8*)&Alds[(wr * 64 + i * 16 + lrow) * 32 + lk];
#pragma unroll
        for (int j = 0; j < 4; ++j)
            bfr[j] = *(const bf16x8*)&Blds[(wc * 64 + j * 16 + lrow) * 32 + lk];
#pragma unroll
        for (int i = 0; i < 4; ++i)
#pragma unroll
            for (int j = 0; j < 4; ++j)
                acc[i][j] = __builtin_amdgcn_mfma_f32_16x16x32_bf16(af[i], bfr[j], acc[i][j], 0, 0, 0);
        __syncthreads();
    }

    int r4 = (l >> 4) * 4;
#pragma unroll
    for (int i = 0; i < 4; ++i)
#pragma unroll
        for (int j = 0; j < 4; ++j)
#pragma unroll
            for (int r = 0; r < 4; ++r) {
                int row = n0 + wr * 64 + i * 16 + r4 + r;
                int col = m0 + wc * 64 + j * 16 + lrow;
                C[(size_t)row * MW + col] = acc[i][j][r];
            }
}

// ---------------- LSTM elementwise epilogue ----------------
__device__ __forceinline__ float sigmoidf_(float x) { return 1.0f / (1.0f + expf(-x)); }

__global__ __launch_bounds__(256) void lstm_ew(
    const float* __restrict__ C,            // [NN][MW] preacts, gate g at col g*256+h
    const float* __restrict__ bf, const float* __restrict__ bi,
    const float* __restrict__ bo, const float* __restrict__ bc,
    const float* __restrict__ cin, float* __restrict__ out) {
    int i = blockIdx.x * blockDim.x + threadIdx.x;  // over NN*HH/4
    if (i >= NN * HH / 4) return;
    int n = i >> 6;           // HH/4 = 64 float4 per row
    int h4 = (i & 63) * 4;
    size_t cb = (size_t)n * MW;
    size_t hb = (size_t)n * HH + h4;
    float4 pf = *(const float4*)&C[cb + 0 * HH + h4];
    float4 pi = *(const float4*)&C[cb + 1 * HH + h4];
    float4 po = *(const float4*)&C[cb + 2 * HH + h4];
    float4 pc = *(const float4*)&C[cb + 3 * HH + h4];
    float4 vbf = *(const float4*)&bf[hb];
    float4 vbi = *(const float4*)&bi[hb];
    float4 vbo = *(const float4*)&bo[hb];
    float4 vbc = *(const float4*)&bc[hb];
    float4 vc  = *(const float4*)&cin[hb];
    float4 hn, cn;
    {
        float fg = sigmoidf_(pf.x + vbf.x), ig = sigmoidf_(pi.x + vbi.x);
        float og = sigmoidf_(po.x + vbo.x), cg = tanhf(pc.x + vbc.x);
        cn.x = ig * cg + fg * vc.x; hn.x = og * tanhf(cn.x);
    }
    {
        float fg = sigmoidf_(pf.y + vbf.y), ig = sigmoidf_(pi.y + vbi.y);
        float og = sigmoidf_(po.y + vbo.y), cg = tanhf(pc.y + vbc.y);
        cn.y = ig * cg + fg * vc.y; hn.y = og * tanhf(cn.y);
    }
    {
        float fg = sigmoidf_(pf.z + vbf.z), ig = sigmoidf_(pi.z + vbi.z);
        float og = sigmoidf_(po.z + vbo.z), cg = tanhf(pc.z + vbc.z);
        cn.z = ig * cg + fg * vc.z; hn.z = og * tanhf(cn.z);
    }
    {
        float fg = sigmoidf_(pf.w + vbf.w), ig = sigmoidf_(pi.w + vbi.w);
        float og = sigmoidf_(po.w + vbo.w), cg = tanhf(pc.w + vbc.w);
        cn.w = ig * cg + fg * vc.w; hn.w = og * tanhf(cn.w);
    }
    *(float4*)&out[hb] = hn;
    *(float4*)&out[(size_t)NN * HH + hb] = cn;
}

// ---------------- launch ----------------
extern "C" void kernel_launch(void* const* d_in, const int* in_sizes, int n_in,
                              void* d_out, int out_size, void* d_ws, size_t ws_size,
                              hipStream_t stream) {
    const float* x   = (const float*)d_in[0];
    const float* h   = (const float*)d_in[1];
    const float* c   = (const float*)d_in[2];
    const float* lap = (const float*)d_in[3];
    const int*   pos = (const int*)d_in[4];
    const float* Wfh = (const float*)d_in[5];
    const float* Wfx = (const float*)d_in[6];
    const float* bf  = (const float*)d_in[7];
    const float* Wih = (const float*)d_in[8];
    const float* Wix = (const float*)d_in[9];
    const float* bi  = (const float*)d_in[10];
    const float* Woh = (const float*)d_in[11];
    const float* Wox = (const float*)d_in[12];
    const float* bo  = (const float*)d_in[13];
    const float* Wch = (const float*)d_in[14];
    const float* Wcx = (const float*)d_in[15];
    const float* bc  = (const float*)d_in[16];
    float* out = (float*)d_out;

    uint8_t* ws = (uint8_t*)d_ws;
    size_t off = 0;
    auto take = [&](size_t bytes) -> void* {
        void* p = ws + off;
        off += (bytes + 255) & ~(size_t)255;
        return p;
    };
    uint32_t* hkey = (uint32_t*)take((size_t)TBL * 4);
    uint32_t* hidx = (uint32_t*)take((size_t)TBL * 4);
    int*      flag = (int*)take(4);
    uint32_t* rcnt = (uint32_t*)take((size_t)NN * 4);
    uint32_t* rptr = (uint32_t*)take((size_t)(NN + 1) * 4);
    uint32_t* curs = (uint32_t*)take((size_t)NN * 4);
    uint32_t* ccol = (uint32_t*)take((size_t)EE * 4);
    float*    cval = (float*)take((size_t)EE * 4);
    float*    Thf  = (float*)take((size_t)3 * NN * HH * 4);   // levels 1..3
    float*    Txf  = (float*)take((size_t)3 * NN * II * 4);   // levels 1..3
    __hip_bfloat16* Amat = (__hip_bfloat16*)take((size_t)NN * KW * 2);  // 25.2 MB
    __hip_bfloat16* Bmat = (__hip_bfloat16*)take((size_t)MW * KW * 2);  // 3.1 MB
    float*    Cpre = (float*)take((size_t)NN * MW * 4);       // 33.5 MB

    init_ws<<<TBL / 256, 256, 0, stream>>>(hkey, hidx, rcnt, pos, flag);
    build_hash<<<EE / 256, 256, 0, stream>>>(pos, flag, hkey, hidx, rcnt);
    scan_rows<<<1, 1024, 0, stream>>>(rcnt, rptr, curs);
    scatter_csr<<<EE / 256, 256, 0, stream>>>(pos, flag, lap, hkey, hidx, curs, ccol, cval);

    pack_A0<<<(NN * 384 + 255) / 256, 256, 0, stream>>>(h, x, Amat);
    pack_B<<<(MW * KW + 255) / 256, 256, 0, stream>>>(Wfh, Wih, Woh, Wch,
                                                      Wfx, Wix, Wox, Wcx, Bmat);

    float* Th1 = Thf;
    float* Th2 = Th1 + (size_t)NN * HH;
    float* Th3 = Th2 + (size_t)NN * HH;
    float* Tx1 = Txf;
    float* Tx2 = Tx1 + (size_t)NN * II;
    float* Tx3 = Tx2 + (size_t)NN * II;

    int sg = NN / 4 + NN / 8;   // 2048 h-blocks + 1024 x-blocks
    // level 1: T1 = L@T0
    spmv_cheb_dual<<<sg, 256, 0, stream>>>(rptr, ccol, cval,
        (const float4*)h,   (const float4*)h,   (float4*)Th1, 256,
        (const float4*)x,   (const float4*)x,   (float4*)Tx1, 1152,
        Amat, 1.0f, 0.0f);
    // level 2: T2 = 2 L@T1 - T0
    spmv_cheb_dual<<<sg, 256, 0, stream>>>(rptr, ccol, cval,
        (const float4*)Th1, (const float4*)h,   (float4*)Th2, 512,
        (const float4*)Tx1, (const float4*)x,   (float4*)Tx2, 1280,
        Amat, 2.0f, -1.0f);
    // level 3: T3 = 2 L@T2 - T1
    spmv_cheb_dual<<<sg, 256, 0, stream>>>(rptr, ccol, cval,
        (const float4*)Th2, (const float4*)Th1, (float4*)Th3, 768,
        (const float4*)Tx2, (const float4*)Tx1, (float4*)Tx3, 1408,
        Amat, 2.0f, -1.0f);

    dim3 gg(MW / 128, NN / 128);
    gemm_mfma<<<gg, 256, 0, stream>>>(Amat, Bmat, Cpre);

    lstm_ew<<<(NN * HH / 4 + 255) / 256, 256, 0, stream>>>(Cpre, bf, bi, bo, bc, c, out);
}

// Round 4
// 210.245 us; speedup vs baseline: 5.0891x; 1.2791x over previous
//
#include <hip/hip_runtime.h>
#include <hip/hip_bf16.h>
#include <cstdint>

// Problem constants (fixed by reference)
#define NN 8192
#define HH 256
#define II 128
#define KORD 4
#define EE 262144
#define KW 1536          // GEMM K = 4*(256+128)
#define MW 1024          // GEMM output cols = 4 gates * 256
#define TBL (1u << 20)   // hash table slots (load factor 0.25)

typedef __attribute__((ext_vector_type(8))) short bf16x8;
typedef __attribute__((ext_vector_type(8))) unsigned short u16x8;
typedef __attribute__((ext_vector_type(4))) float f32x4;

__device__ __forceinline__ float bf2f(unsigned short u) {
    union { uint32_t i; float f; } x; x.i = ((uint32_t)u) << 16; return x.f;
}
__device__ __forceinline__ unsigned short f2bf(float f) {
    __hip_bfloat16 b = __float2bfloat16(f);
    return *(unsigned short*)&b;
}

// ---------------- pos layout handling (int32 vs int64 words) ----------------
__device__ __forceinline__ void read_pos(const int* __restrict__ pos, int flag,
                                         int e, int& r, int& c) {
    if (flag) { r = pos[4 * e]; c = pos[4 * e + 2]; }   // int64 little-endian
    else      { r = pos[2 * e]; c = pos[2 * e + 1]; }   // int32
}

// ---------------- init (+ layout detect in block 0) ----------------
__global__ void init_ws(uint32_t* __restrict__ hkey, uint32_t* __restrict__ hidx,
                        uint32_t* __restrict__ rcnt,
                        const int* __restrict__ pos, int* __restrict__ flag) {
    int i = blockIdx.x * blockDim.x + threadIdx.x;
    if (i < (int)TBL) { hkey[i] = 0xFFFFFFFFu; hidx[i] = 0u; }
    if (i < NN) rcnt[i] = 0u;
    if (i == 0) {
        int f = 1;
        for (int k = 0; k < 128; ++k) {
            if (pos[2 * k + 1] != 0) { f = 0; break; }
        }
        *flag = f;
    }
}

__device__ __forceinline__ uint32_t hash_key(uint32_t key) {
    return (key * 2654435761u) >> 6 & (TBL - 1u);
}

// ---------------- dedupe (last write wins) + row count ----------------
__global__ void build_hash(const int* __restrict__ pos, const int* __restrict__ flagp,
                           uint32_t* __restrict__ hkey, uint32_t* __restrict__ hidx,
                           uint32_t* __restrict__ rcnt) {
    int e = blockIdx.x * blockDim.x + threadIdx.x;
    if (e >= EE) return;
    int flag = *flagp;
    int r, c; read_pos(pos, flag, e, r, c);
    uint32_t key = (uint32_t)r * (uint32_t)NN + (uint32_t)c;
    uint32_t slot = hash_key(key);
    for (;;) {
        uint32_t prev = atomicCAS(&hkey[slot], 0xFFFFFFFFu, key);
        if (prev == 0xFFFFFFFFu || prev == key) {
            atomicMax(&hidx[slot], (uint32_t)(e + 1));
            break;
        }
        slot = (slot + 1u) & (TBL - 1u);
    }
    atomicAdd(&rcnt[r], 1u);
}

__global__ __launch_bounds__(1024) void scan_rows(const uint32_t* __restrict__ cnt,
                                                  uint32_t* __restrict__ rptr,
                                                  uint32_t* __restrict__ curs) {
    __shared__ uint32_t part[1024];
    int t = threadIdx.x;
    uint32_t loc[8];
    uint32_t s = 0;
#pragma unroll
    for (int i = 0; i < 8; ++i) { loc[i] = s; s += cnt[t * 8 + i]; }
    part[t] = s;
    __syncthreads();
    for (int o = 1; o < 1024; o <<= 1) {
        uint32_t xv = part[t];
        uint32_t yv = (t >= o) ? part[t - o] : 0u;
        __syncthreads();
        part[t] = xv + yv;
        __syncthreads();
    }
    uint32_t base = part[t] - s;  // exclusive prefix for this thread
#pragma unroll
    for (int i = 0; i < 8; ++i) {
        uint32_t v = base + loc[i];
        rptr[t * 8 + i] = v;
        curs[t * 8 + i] = v;
    }
    if (t == 1023) rptr[NN] = part[1023];
}

// scatter with fused dedup; packs (col, val_bits) into uint2
__global__ void scatter_csr(const int* __restrict__ pos, const int* __restrict__ flagp,
                            const float* __restrict__ lap,
                            const uint32_t* __restrict__ hkey, const uint32_t* __restrict__ hidx,
                            uint32_t* __restrict__ curs, uint2* __restrict__ cpack) {
    int e = blockIdx.x * blockDim.x + threadIdx.x;
    if (e >= EE) return;
    int flag = *flagp;
    int r, c; read_pos(pos, flag, e, r, c);
    uint32_t key = (uint32_t)r * (uint32_t)NN + (uint32_t)c;
    uint32_t slot = hash_key(key);
    while (hkey[slot] != key) slot = (slot + 1u) & (TBL - 1u);
    float v = (hidx[slot] == (uint32_t)(e + 1)) ? lap[e] : 0.0f;
    uint32_t dst = atomicAdd(&curs[r], 1u);
    uint2 p; p.x = (uint32_t)c; p.y = __float_as_uint(v);
    cpack[dst] = p;
}

// ---------------- SpMV on bf16 state: f32 accum, 16B gathers, unroll 4 ------
// o = a * (L @ X)[r, lane*8..+8] + b * P[r, ...]; writes bf16 to Y and Amat.
template <int F>  // F = row length in bf16 elems (256 or 128)
__device__ __forceinline__ void spmv_seg(
    const uint32_t* __restrict__ rptr, const uint2* __restrict__ cp,
    const unsigned short* __restrict__ Xb, const unsigned short* __restrict__ Pb,
    unsigned short* __restrict__ Yb, unsigned short* __restrict__ Am, int colbase,
    float a, float b, int r, int lane) {
    uint32_t s = rptr[r], e = rptr[r + 1];
    int off = lane * 8;
    float acc[8];
#pragma unroll
    for (int j = 0; j < 8; ++j) acc[j] = 0.0f;
    uint32_t i = s;
    for (; i + 4 <= e; i += 4) {
        uint2 p0 = cp[i], p1 = cp[i + 1], p2 = cp[i + 2], p3 = cp[i + 3];
        u16x8 g0 = *(const u16x8*)&Xb[(size_t)p0.x * F + off];
        u16x8 g1 = *(const u16x8*)&Xb[(size_t)p1.x * F + off];
        u16x8 g2 = *(const u16x8*)&Xb[(size_t)p2.x * F + off];
        u16x8 g3 = *(const u16x8*)&Xb[(size_t)p3.x * F + off];
        float v0 = __uint_as_float(p0.y), v1 = __uint_as_float(p1.y);
        float v2 = __uint_as_float(p2.y), v3 = __uint_as_float(p3.y);
#pragma unroll
        for (int j = 0; j < 8; ++j)
            acc[j] += v0 * bf2f(g0[j]) + v1 * bf2f(g1[j]) +
                      v2 * bf2f(g2[j]) + v3 * bf2f(g3[j]);
    }
    for (; i < e; ++i) {
        uint2 p0 = cp[i];
        u16x8 g0 = *(const u16x8*)&Xb[(size_t)p0.x * F + off];
        float v0 = __uint_as_float(p0.y);
#pragma unroll
        for (int j = 0; j < 8; ++j) acc[j] += v0 * bf2f(g0[j]);
    }
    u16x8 ob;
    if (b != 0.0f) {
        u16x8 pv = *(const u16x8*)&Pb[(size_t)r * F + off];
#pragma unroll
        for (int j = 0; j < 8; ++j) ob[j] = f2bf(a * acc[j] + b * bf2f(pv[j]));
    } else {
#pragma unroll
        for (int j = 0; j < 8; ++j) ob[j] = f2bf(a * acc[j]);
    }
    *(u16x8*)&Yb[(size_t)r * F + off] = ob;
    *(u16x8*)&Am[(size_t)r * KW + colbase + off] = ob;
}

// one launch = one Chebyshev level for BOTH h (F=256) and x (F=128)
#define NBH (NN / 8)    // h: 32 lanes/row, 8 rows/block
#define NBX (NN / 16)   // x: 16 lanes/row, 16 rows/block
__global__ __launch_bounds__(256) void spmv_cheb_dual(
    const uint32_t* __restrict__ rptr, const uint2* __restrict__ cp,
    const unsigned short* __restrict__ Xh, const unsigned short* __restrict__ Ph,
    unsigned short* __restrict__ Yh, int cbh,
    const unsigned short* __restrict__ Xx, const unsigned short* __restrict__ Px,
    unsigned short* __restrict__ Yx, int cbx,
    unsigned short* __restrict__ Am, float a, float b) {
    int bid = blockIdx.x, t = threadIdx.x;
    if (bid < NBH) {
        int r = bid * 8 + (t >> 5), lane = t & 31;
        spmv_seg<HH>(rptr, cp, Xh, Ph, Yh, Am, cbh, a, b, r, lane);
    } else {
        int r = (bid - NBH) * 16 + (t >> 4), lane = t & 15;
        spmv_seg<II>(rptr, cp, Xx, Px, Yx, Am, cbx, a, b, r, lane);
    }
}

// ---------------- level-0 pack: h,x -> bf16 state + A cols ----------------
__global__ void pack_T0(const float* __restrict__ h, const float* __restrict__ x,
                        unsigned short* __restrict__ Hb, unsigned short* __restrict__ Xb,
                        unsigned short* __restrict__ Am) {
    int idx = blockIdx.x * blockDim.x + threadIdx.x;  // over NN*96 (4-elem units)
    if (idx >= NN * 96) return;
    int n, q, col;
    const float* src;
    unsigned short* st;
    if (idx < NN * 64) { n = idx >> 6; q = (idx & 63) * 4; src = &h[(size_t)n * HH + q]; st = &Hb[(size_t)n * HH + q]; col = q; }
    else { int ix = idx - NN * 64; n = ix >> 5; q = (ix & 31) * 4; src = &x[(size_t)n * II + q]; st = &Xb[(size_t)n * II + q]; col = 1024 + q; }
    float4 v = *(const float4*)src;
    ushort4 pk;
    pk.x = f2bf(v.x); pk.y = f2bf(v.y); pk.z = f2bf(v.z); pk.w = f2bf(v.w);
    *(ushort4*)st = pk;
    *(ushort4*)&Am[(size_t)n * KW + col] = pk;
}

// B matrix [1024][1536]: row m = g*256+h
__global__ void pack_B(const float* __restrict__ Wfh, const float* __restrict__ Wih,
                       const float* __restrict__ Woh, const float* __restrict__ Wch,
                       const float* __restrict__ Wfx, const float* __restrict__ Wix,
                       const float* __restrict__ Wox, const float* __restrict__ Wcx,
                       __hip_bfloat16* __restrict__ Bm) {
    int idx = blockIdx.x * blockDim.x + threadIdx.x;  // over MW*KW
    if (idx >= MW * KW) return;
    int m = idx / KW, j = idx - m * KW;
    int g = m >> 8, hh = m & 255;
    const float* Wh = (g == 0) ? Wfh : (g == 1) ? Wih : (g == 2) ? Woh : Wch;
    const float* Wx = (g == 0) ? Wfx : (g == 1) ? Wix : (g == 2) ? Wox : Wcx;
    float v;
    if (j < 1024) { int k = j >> 8, f = j & 255; v = Wh[((size_t)k * HH + hh) * HH + f]; }
    else { int jj = j - 1024; int k = jj >> 7, f = jj & 127; v = Wx[((size_t)k * HH + hh) * II + f]; }
    Bm[idx] = __float2bfloat16(v);
}

// ---------------- bf16 MFMA GEMM (m97 structure + XCD-chunked swizzle) ------
__device__ __forceinline__ void gload_lds16(const void* g, void* l) {
    __builtin_amdgcn_global_load_lds(
        (const __attribute__((address_space(1))) void*)g,
        (__attribute__((address_space(3))) void*)l, 16, 0, 0);
}

__global__ __launch_bounds__(256) void gemm_mfma(
    const __hip_bfloat16* __restrict__ A,   // [NN][KW]
    const __hip_bfloat16* __restrict__ B,   // [MW][KW]
    float* __restrict__ C) {                // [NN][MW]
    __shared__ short Alds[128 * 32];
    __shared__ short Blds[128 * 32];
    // XCD-chunked bijective swizzle: 512 blocks, XCD k gets row-tiles k*8..k*8+7
    int bid = blockIdx.x;
    int sw = (bid & 7) * 64 + (bid >> 3);
    int m0 = (sw & 7) * 128;    // col tile
    int n0 = (sw >> 3) * 128;   // row tile
    int t = threadIdx.x;
    int w = t >> 6, l = t & 63;
    int wr = w >> 1, wc = w & 1;
    int lrow = l & 15, lk = (l >> 4) * 8;

    f32x4 acc[4][4];
#pragma unroll
    for (int i = 0; i < 4; ++i)
#pragma unroll
        for (int j = 0; j < 4; ++j) acc[i][j] = (f32x4)0.0f;

    for (int k0 = 0; k0 < KW; k0 += 32) {
#pragma unroll
        for (int s = 0; s < 2; ++s) {
            int e = (s * 256 + t) * 8;       // bf16 element index in tile
            int row = e >> 5, kk = e & 31;
            gload_lds16(&A[(size_t)(n0 + row) * KW + k0 + kk], &Alds[e]);
            gload_lds16(&B[(size_t)(m0 + row) * KW + k0 + kk], &Blds[e]);
        }
        __syncthreads();
        bf16x8 af[4], bfr[4];
#pragma unroll
        for (int i = 0; i < 4; ++i)
            af[i] = *(const bf16x8*)&Alds[(wr * 64 + i * 16 + lrow) * 32 + lk];
#pragma unroll
        for (int j = 0; j < 4; ++j)
            bfr[j] = *(const bf16x8*)&Blds[(wc * 64 + j * 16 + lrow) * 32 + lk];
#pragma unroll
        for (int i = 0; i < 4; ++i)
#pragma unroll
            for (int j = 0; j < 4; ++j)
                acc[i][j] = __builtin_amdgcn_mfma_f32_16x16x32_bf16(af[i], bfr[j], acc[i][j], 0, 0, 0);
        __syncthreads();
    }

    int r4 = (l >> 4) * 4;
#pragma unroll
    for (int i = 0; i < 4; ++i)
#pragma unroll
        for (int j = 0; j < 4; ++j)
#pragma unroll
            for (int r = 0; r < 4; ++r) {
                int row = n0 + wr * 64 + i * 16 + r4 + r;
                int col = m0 + wc * 64 + j * 16 + lrow;
                C[(size_t)row * MW + col] = acc[i][j][r];
            }
}

// ---------------- LSTM elementwise epilogue ----------------
__device__ __forceinline__ float sigmoidf_(float x) { return 1.0f / (1.0f + expf(-x)); }

__global__ __launch_bounds__(256) void lstm_ew(
    const float* __restrict__ C,            // [NN][MW] preacts, gate g at col g*256+h
    const float* __restrict__ bf, const float* __restrict__ bi,
    const float* __restrict__ bo, const float* __restrict__ bc,
    const float* __restrict__ cin, float* __restrict__ out) {
    int i = blockIdx.x * blockDim.x + threadIdx.x;  // over NN*HH/4
    if (i >= NN * HH / 4) return;
    int n = i >> 6;           // HH/4 = 64 float4 per row
    int h4 = (i & 63) * 4;
    size_t cb = (size_t)n * MW;
    size_t hb = (size_t)n * HH + h4;
    float4 pf = *(const float4*)&C[cb + 0 * HH + h4];
    float4 pi = *(const float4*)&C[cb + 1 * HH + h4];
    float4 po = *(const float4*)&C[cb + 2 * HH + h4];
    float4 pc = *(const float4*)&C[cb + 3 * HH + h4];
    float4 vbf = *(const float4*)&bf[hb];
    float4 vbi = *(const float4*)&bi[hb];
    float4 vbo = *(const float4*)&bo[hb];
    float4 vbc = *(const float4*)&bc[hb];
    float4 vc  = *(const float4*)&cin[hb];
    float4 hn, cn;
    {
        float fg = sigmoidf_(pf.x + vbf.x), ig = sigmoidf_(pi.x + vbi.x);
        float og = sigmoidf_(po.x + vbo.x), cg = tanhf(pc.x + vbc.x);
        cn.x = ig * cg + fg * vc.x; hn.x = og * tanhf(cn.x);
    }
    {
        float fg = sigmoidf_(pf.y + vbf.y), ig = sigmoidf_(pi.y + vbi.y);
        float og = sigmoidf_(po.y + vbo.y), cg = tanhf(pc.y + vbc.y);
        cn.y = ig * cg + fg * vc.y; hn.y = og * tanhf(cn.y);
    }
    {
        float fg = sigmoidf_(pf.z + vbf.z), ig = sigmoidf_(pi.z + vbi.z);
        float og = sigmoidf_(po.z + vbo.z), cg = tanhf(pc.z + vbc.z);
        cn.z = ig * cg + fg * vc.z; hn.z = og * tanhf(cn.z);
    }
    {
        float fg = sigmoidf_(pf.w + vbf.w), ig = sigmoidf_(pi.w + vbi.w);
        float og = sigmoidf_(po.w + vbo.w), cg = tanhf(pc.w + vbc.w);
        cn.w = ig * cg + fg * vc.w; hn.w = og * tanhf(cn.w);
    }
    *(float4*)&out[hb] = hn;
    *(float4*)&out[(size_t)NN * HH + hb] = cn;
}

// ---------------- launch ----------------
extern "C" void kernel_launch(void* const* d_in, const int* in_sizes, int n_in,
                              void* d_out, int out_size, void* d_ws, size_t ws_size,
                              hipStream_t stream) {
    const float* x   = (const float*)d_in[0];
    const float* h   = (const float*)d_in[1];
    const float* c   = (const float*)d_in[2];
    const float* lap = (const float*)d_in[3];
    const int*   pos = (const int*)d_in[4];
    const float* Wfh = (const float*)d_in[5];
    const float* Wfx = (const float*)d_in[6];
    const float* bf  = (const float*)d_in[7];
    const float* Wih = (const float*)d_in[8];
    const float* Wix = (const float*)d_in[9];
    const float* bi  = (const float*)d_in[10];
    const float* Woh = (const float*)d_in[11];
    const float* Wox = (const float*)d_in[12];
    const float* bo  = (const float*)d_in[13];
    const float* Wch = (const float*)d_in[14];
    const float* Wcx = (const float*)d_in[15];
    const float* bc  = (const float*)d_in[16];
    float* out = (float*)d_out;

    uint8_t* ws = (uint8_t*)d_ws;
    size_t off = 0;
    auto take = [&](size_t bytes) -> void* {
        void* p = ws + off;
        off += (bytes + 255) & ~(size_t)255;
        return p;
    };
    uint32_t* hkey = (uint32_t*)take((size_t)TBL * 4);
    uint32_t* hidx = (uint32_t*)take((size_t)TBL * 4);
    int*      flag = (int*)take(4);
    uint32_t* rcnt = (uint32_t*)take((size_t)NN * 4);
    uint32_t* rptr = (uint32_t*)take((size_t)(NN + 1) * 4);
    uint32_t* curs = (uint32_t*)take((size_t)NN * 4);
    uint2*    cpack= (uint2*)take((size_t)EE * 8);
    unsigned short* Hb = (unsigned short*)take((size_t)4 * NN * HH * 2);  // 16.8 MB
    unsigned short* Xb = (unsigned short*)take((size_t)4 * NN * II * 2);  //  8.4 MB
    unsigned short* Amat = (unsigned short*)take((size_t)NN * KW * 2);    // 25.2 MB
    __hip_bfloat16* Bmat = (__hip_bfloat16*)take((size_t)MW * KW * 2);    //  3.1 MB
    float*    Cpre = (float*)take((size_t)NN * MW * 4);                   // 33.5 MB

    init_ws<<<TBL / 256, 256, 0, stream>>>(hkey, hidx, rcnt, pos, flag);
    build_hash<<<EE / 256, 256, 0, stream>>>(pos, flag, hkey, hidx, rcnt);
    scan_rows<<<1, 1024, 0, stream>>>(rcnt, rptr, curs);
    scatter_csr<<<EE / 256, 256, 0, stream>>>(pos, flag, lap, hkey, hidx, curs, cpack);

    pack_T0<<<(NN * 96 + 255) / 256, 256, 0, stream>>>(h, x, Hb, Xb, Amat);
    pack_B<<<(MW * KW + 255) / 256, 256, 0, stream>>>(Wfh, Wih, Woh, Wch,
                                                      Wfx, Wix, Wox, Wcx, Bmat);

    unsigned short* Hb0 = Hb;
    unsigned short* Hb1 = Hb + (size_t)NN * HH;
    unsigned short* Hb2 = Hb1 + (size_t)NN * HH;
    unsigned short* Hb3 = Hb2 + (size_t)NN * HH;
    unsigned short* Xb0 = Xb;
    unsigned short* Xb1 = Xb + (size_t)NN * II;
    unsigned short* Xb2 = Xb1 + (size_t)NN * II;
    unsigned short* Xb3 = Xb2 + (size_t)NN * II;

    int sg = NBH + NBX;   // 1024 + 512 blocks
    // level 1: T1 = L@T0
    spmv_cheb_dual<<<sg, 256, 0, stream>>>(rptr, cpack,
        Hb0, Hb0, Hb1, 256, Xb0, Xb0, Xb1, 1152, Amat, 1.0f, 0.0f);
    // level 2: T2 = 2 L@T1 - T0
    spmv_cheb_dual<<<sg, 256, 0, stream>>>(rptr, cpack,
        Hb1, Hb0, Hb2, 512, Xb1, Xb0, Xb2, 1280, Amat, 2.0f, -1.0f);
    // level 3: T3 = 2 L@T2 - T1
    spmv_cheb_dual<<<sg, 256, 0, stream>>>(rptr, cpack,
        Hb2, Hb1, Hb3, 768, Xb2, Xb1, Xb3, 1408, Amat, 2.0f, -1.0f);

    gemm_mfma<<<512, 256, 0, stream>>>((const __hip_bfloat16*)Amat, Bmat, Cpre);

    lstm_ew<<<(NN * HH / 4 + 255) / 256, 256, 0, stream>>>(Cpre, bf, bi, bo, bc, c, out);
}

// Round 6
// 198.976 us; speedup vs baseline: 5.3773x; 1.0566x over previous
//
#include <hip/hip_runtime.h>
#include <hip/hip_bf16.h>
#include <cstdint>

// Problem constants (fixed by reference)
#define NN 8192
#define HH 256
#define II 128
#define KORD 4
#define EE 262144
#define KW 1536          // GEMM K = 4*(256+128)
#define MW 1024          // GEMM output cols = 4 gates * 256
#define TBL (1u << 20)   // hash table slots (load factor 0.25)

typedef __attribute__((ext_vector_type(8))) short bf16x8;
typedef __attribute__((ext_vector_type(8))) unsigned short u16x8;
typedef __attribute__((ext_vector_type(4))) float f32x4;

__device__ __forceinline__ float bf2f(unsigned short u) {
    union { uint32_t i; float f; } x; x.i = ((uint32_t)u) << 16; return x.f;
}
__device__ __forceinline__ unsigned short f2bf(float f) {
    __hip_bfloat16 b = __float2bfloat16(f);
    return *(unsigned short*)&b;
}

// ---------------- pos layout handling (int32 vs int64 words) ----------------
__device__ __forceinline__ void read_pos(const int* __restrict__ pos, int flag,
                                         int e, int& r, int& c) {
    if (flag) { r = pos[4 * e]; c = pos[4 * e + 2]; }   // int64 little-endian
    else      { r = pos[2 * e]; c = pos[2 * e + 1]; }   // int32
}

// ---------------- init (+ layout detect in block 0) ----------------
__global__ void init_ws(uint32_t* __restrict__ hkey, uint32_t* __restrict__ hidx,
                        uint32_t* __restrict__ rcnt,
                        const int* __restrict__ pos, int* __restrict__ flag) {
    int i = blockIdx.x * blockDim.x + threadIdx.x;
    if (i < (int)TBL) { hkey[i] = 0xFFFFFFFFu; hidx[i] = 0u; }
    if (i < NN) rcnt[i] = 0u;
    if (i == 0) {
        int f = 1;
        for (int k = 0; k < 128; ++k) {
            if (pos[2 * k + 1] != 0) { f = 0; break; }
        }
        *flag = f;
    }
}

__device__ __forceinline__ uint32_t hash_key(uint32_t key) {
    return (key * 2654435761u) >> 6 & (TBL - 1u);
}

// ---------------- dedupe (last write wins) + row count ----------------
__global__ void build_hash(const int* __restrict__ pos, const int* __restrict__ flagp,
                           uint32_t* __restrict__ hkey, uint32_t* __restrict__ hidx,
                           uint32_t* __restrict__ rcnt) {
    int e = blockIdx.x * blockDim.x + threadIdx.x;
    if (e >= EE) return;
    int flag = *flagp;
    int r, c; read_pos(pos, flag, e, r, c);
    uint32_t key = (uint32_t)r * (uint32_t)NN + (uint32_t)c;
    uint32_t slot = hash_key(key);
    for (;;) {
        uint32_t prev = atomicCAS(&hkey[slot], 0xFFFFFFFFu, key);
        if (prev == 0xFFFFFFFFu || prev == key) {
            atomicMax(&hidx[slot], (uint32_t)(e + 1));
            break;
        }
        slot = (slot + 1u) & (TBL - 1u);
    }
    atomicAdd(&rcnt[r], 1u);
}

__global__ __launch_bounds__(1024) void scan_rows(const uint32_t* __restrict__ cnt,
                                                  uint32_t* __restrict__ rptr,
                                                  uint32_t* __restrict__ curs) {
    __shared__ uint32_t part[1024];
    int t = threadIdx.x;
    uint32_t loc[8];
    uint32_t s = 0;
#pragma unroll
    for (int i = 0; i < 8; ++i) { loc[i] = s; s += cnt[t * 8 + i]; }
    part[t] = s;
    __syncthreads();
    for (int o = 1; o < 1024; o <<= 1) {
        uint32_t xv = part[t];
        uint32_t yv = (t >= o) ? part[t - o] : 0u;
        __syncthreads();
        part[t] = xv + yv;
        __syncthreads();
    }
    uint32_t base = part[t] - s;  // exclusive prefix for this thread
#pragma unroll
    for (int i = 0; i < 8; ++i) {
        uint32_t v = base + loc[i];
        rptr[t * 8 + i] = v;
        curs[t * 8 + i] = v;
    }
    if (t == 1023) rptr[NN] = part[1023];
}

// scatter with fused dedup; packs (col, val_bits) into uint2
__global__ void scatter_csr(const int* __restrict__ pos, const int* __restrict__ flagp,
                            const float* __restrict__ lap,
                            const uint32_t* __restrict__ hkey, const uint32_t* __restrict__ hidx,
                            uint32_t* __restrict__ curs, uint2* __restrict__ cpack) {
    int e = blockIdx.x * blockDim.x + threadIdx.x;
    if (e >= EE) return;
    int flag = *flagp;
    int r, c; read_pos(pos, flag, e, r, c);
    uint32_t key = (uint32_t)r * (uint32_t)NN + (uint32_t)c;
    uint32_t slot = hash_key(key);
    while (hkey[slot] != key) slot = (slot + 1u) & (TBL - 1u);
    float v = (hidx[slot] == (uint32_t)(e + 1)) ? lap[e] : 0.0f;
    uint32_t dst = atomicAdd(&curs[r], 1u);
    uint2 p; p.x = (uint32_t)c; p.y = __float_as_uint(v);
    cpack[dst] = p;
}

// ---------------- SpMV on bf16 state: f32 accum, 16B gathers, unroll 4 ------
// (round-4 proven body, + LAST template to skip the dead level-3 Y store)
template <int F, bool LAST>
__device__ __forceinline__ void spmv_seg(
    const uint32_t* __restrict__ rptr, const uint2* __restrict__ cp,
    const unsigned short* __restrict__ Xb, const unsigned short* __restrict__ Pb,
    unsigned short* __restrict__ Yb, unsigned short* __restrict__ Am, int colbase,
    float a, float b, int r, int lane) {
    uint32_t s = rptr[r], e = rptr[r + 1];
    int off = lane * 8;
    float acc[8];
#pragma unroll
    for (int j = 0; j < 8; ++j) acc[j] = 0.0f;
    uint32_t i = s;
    for (; i + 4 <= e; i += 4) {
        uint2 p0 = cp[i], p1 = cp[i + 1], p2 = cp[i + 2], p3 = cp[i + 3];
        u16x8 g0 = *(const u16x8*)&Xb[(size_t)p0.x * F + off];
        u16x8 g1 = *(const u16x8*)&Xb[(size_t)p1.x * F + off];
        u16x8 g2 = *(const u16x8*)&Xb[(size_t)p2.x * F + off];
        u16x8 g3 = *(const u16x8*)&Xb[(size_t)p3.x * F + off];
        float v0 = __uint_as_float(p0.y), v1 = __uint_as_float(p1.y);
        float v2 = __uint_as_float(p2.y), v3 = __uint_as_float(p3.y);
#pragma unroll
        for (int j = 0; j < 8; ++j)
            acc[j] += v0 * bf2f(g0[j]) + v1 * bf2f(g1[j]) +
                      v2 * bf2f(g2[j]) + v3 * bf2f(g3[j]);
    }
    for (; i < e; ++i) {
        uint2 p0 = cp[i];
        u16x8 g0 = *(const u16x8*)&Xb[(size_t)p0.x * F + off];
        float v0 = __uint_as_float(p0.y);
#pragma unroll
        for (int j = 0; j < 8; ++j) acc[j] += v0 * bf2f(g0[j]);
    }
    u16x8 ob;
    if (b != 0.0f) {
        u16x8 pv = *(const u16x8*)&Pb[(size_t)r * F + off];
#pragma unroll
        for (int j = 0; j < 8; ++j) ob[j] = f2bf(a * acc[j] + b * bf2f(pv[j]));
    } else {
#pragma unroll
        for (int j = 0; j < 8; ++j) ob[j] = f2bf(a * acc[j]);
    }
    if (!LAST) *(u16x8*)&Yb[(size_t)r * F + off] = ob;
    *(u16x8*)&Am[(size_t)r * KW + colbase + off] = ob;
}

// one launch = one Chebyshev level for BOTH h (F=256) and x (F=128)
#define NBH (NN / 8)    // h: 32 lanes/row, 8 rows/block
#define NBX (NN / 16)   // x: 16 lanes/row, 16 rows/block
template <bool LAST>
__global__ __launch_bounds__(256) void spmv_cheb_dual(
    const uint32_t* __restrict__ rptr, const uint2* __restrict__ cp,
    const unsigned short* __restrict__ Xh, const unsigned short* __restrict__ Ph,
    unsigned short* __restrict__ Yh, int cbh,
    const unsigned short* __restrict__ Xx, const unsigned short* __restrict__ Px,
    unsigned short* __restrict__ Yx, int cbx,
    unsigned short* __restrict__ Am, float a, float b) {
    int bid = blockIdx.x, t = threadIdx.x;
    if (bid < NBH) {
        int r = bid * 8 + (t >> 5), lane = t & 31;
        spmv_seg<HH, LAST>(rptr, cp, Xh, Ph, Yh, Am, cbh, a, b, r, lane);
    } else {
        int r = (bid - NBH) * 16 + (t >> 4), lane = t & 15;
        spmv_seg<II, LAST>(rptr, cp, Xx, Px, Yx, Am, cbx, a, b, r, lane);
    }
}

// ---------------- level-0 pack: h,x -> bf16 state + A cols ----------------
__global__ void pack_T0(const float* __restrict__ h, const float* __restrict__ x,
                        unsigned short* __restrict__ Hb, unsigned short* __restrict__ Xb,
                        unsigned short* __restrict__ Am) {
    int idx = blockIdx.x * blockDim.x + threadIdx.x;  // over NN*96 (4-elem units)
    if (idx >= NN * 96) return;
    int n, q, col;
    const float* src;
    unsigned short* st;
    if (idx < NN * 64) { n = idx >> 6; q = (idx & 63) * 4; src = &h[(size_t)n * HH + q]; st = &Hb[(size_t)n * HH + q]; col = q; }
    else { int ix = idx - NN * 64; n = ix >> 5; q = (ix & 31) * 4; src = &x[(size_t)n * II + q]; st = &Xb[(size_t)n * II + q]; col = 1024 + q; }
    float4 v = *(const float4*)src;
    ushort4 pk;
    pk.x = f2bf(v.x); pk.y = f2bf(v.y); pk.z = f2bf(v.z); pk.w = f2bf(v.w);
    *(ushort4*)st = pk;
    *(ushort4*)&Am[(size_t)n * KW + col] = pk;
}

// B matrix [1024][1536], gate-panel interleave:
// pcol = (h>>5)*128 + g*32 + (h&31)  <->  g = (pcol>>5)&3, h = (pcol>>7)*32 + (pcol&31)
__global__ void pack_B(const float* __restrict__ Wfh, const float* __restrict__ Wih,
                       const float* __restrict__ Woh, const float* __restrict__ Wch,
                       const float* __restrict__ Wfx, const float* __restrict__ Wix,
                       const float* __restrict__ Wox, const float* __restrict__ Wcx,
                       __hip_bfloat16* __restrict__ Bm) {
    int idx = blockIdx.x * blockDim.x + threadIdx.x;  // over MW*KW
    if (idx >= MW * KW) return;
    int pcol = idx / KW, j = idx - pcol * KW;
    int g = (pcol >> 5) & 3;
    int hh = (pcol >> 7) * 32 + (pcol & 31);
    const float* Wh = (g == 0) ? Wfh : (g == 1) ? Wih : (g == 2) ? Woh : Wch;
    const float* Wx = (g == 0) ? Wfx : (g == 1) ? Wix : (g == 2) ? Wox : Wcx;
    float v;
    if (j < 1024) { int k = j >> 8, f = j & 255; v = Wh[((size_t)k * HH + hh) * HH + f]; }
    else { int jj = j - 1024; int k = jj >> 7, f = jj & 127; v = Wx[((size_t)k * HH + hh) * II + f]; }
    Bm[idx] = __float2bfloat16(v);
}

// ---------------- bf16 MFMA GEMM + fused LSTM epilogue ----------------------
__device__ __forceinline__ void gload_lds16(const void* g, void* l) {
    __builtin_amdgcn_global_load_lds(
        (const __attribute__((address_space(1))) void*)g,
        (__attribute__((address_space(3))) void*)l, 16, 0, 0);
}

__device__ __forceinline__ float sigmoidf_(float x) { return 1.0f / (1.0f + expf(-x)); }

__global__ __launch_bounds__(256) void gemm_fused(
    const __hip_bfloat16* __restrict__ A,   // [NN][KW]
    const __hip_bfloat16* __restrict__ B,   // [MW][KW], gate-panel layout
    const float* __restrict__ bfb, const float* __restrict__ bib,
    const float* __restrict__ bob, const float* __restrict__ bcb,
    const float* __restrict__ cin, float* __restrict__ out) {
    __shared__ short Alds[128 * 32];
    __shared__ short Blds[128 * 32];
    // XCD-chunked bijective swizzle: 512 blocks
    int bid = blockIdx.x;
    int sw = (bid & 7) * 64 + (bid >> 3);
    int m0 = (sw & 7) * 128;    // pcol tile
    int n0 = (sw >> 3) * 128;   // row tile
    int t = threadIdx.x;
    int w = t >> 6, l = t & 63;     // wave w owns rows n0+w*32..+31, all 128 cols
    int lrow = l & 15, lk = (l >> 4) * 8;

    f32x4 acc[2][8];
#pragma unroll
    for (int i = 0; i < 2; ++i)
#pragma unroll
        for (int j = 0; j < 8; ++j) acc[i][j] = (f32x4)0.0f;

    for (int k0 = 0; k0 < KW; k0 += 32) {
#pragma unroll
        for (int s = 0; s < 2; ++s) {
            int e = (s * 256 + t) * 8;       // bf16 element index in tile
            int row = e >> 5, kk = e & 31;
            gload_lds16(&A[(size_t)(n0 + row) * KW + k0 + kk], &Alds[e]);
            gload_lds16(&B[(size_t)(m0 + row) * KW + k0 + kk], &Blds[e]);
        }
        __syncthreads();
        bf16x8 af[2], bfr[8];
#pragma unroll
        for (int i = 0; i < 2; ++i)
            af[i] = *(const bf16x8*)&Alds[(w * 32 + i * 16 + lrow) * 32 + lk];
#pragma unroll
        for (int j = 0; j < 8; ++j)
            bfr[j] = *(const bf16x8*)&Blds[(j * 16 + lrow) * 32 + lk];
#pragma unroll
        for (int i = 0; i < 2; ++i)
#pragma unroll
            for (int j = 0; j < 8; ++j)
                acc[i][j] = __builtin_amdgcn_mfma_f32_16x16x32_bf16(af[i], bfr[j], acc[i][j], 0, 0, 0);
        __syncthreads();
    }

    // fused LSTM epilogue: lane holds all 4 gates for its (row, h) pairs
    // fragment j = g*2 + hb ; h = (m0>>7)*32 + hb*16 + lrow
    int hbase = (m0 >> 7) * 32;
    int r4 = (l >> 4) * 4;
#pragma unroll
    for (int i = 0; i < 2; ++i) {
#pragma unroll
        for (int hb = 0; hb < 2; ++hb) {
            int hcol = hbase + hb * 16 + lrow;
            f32x4 pf = acc[i][0 * 2 + hb];
            f32x4 pi = acc[i][1 * 2 + hb];
            f32x4 po = acc[i][2 * 2 + hb];
            f32x4 pc = acc[i][3 * 2 + hb];
#pragma unroll
            for (int k = 0; k < 4; ++k) {
                int row = n0 + w * 32 + i * 16 + r4 + k;
                size_t idx = (size_t)row * HH + hcol;
                float fg = sigmoidf_(pf[k] + bfb[idx]);
                float ig = sigmoidf_(pi[k] + bib[idx]);
                float og = sigmoidf_(po[k] + bob[idx]);
                float cg = tanhf(pc[k] + bcb[idx]);
                float cn = ig * cg + fg * cin[idx];
                float hn = og * tanhf(cn);
                out[idx] = hn;
                out[(size_t)NN * HH + idx] = cn;
            }
        }
    }
}

// ---------------- launch ----------------
extern "C" void kernel_launch(void* const* d_in, const int* in_sizes, int n_in,
                              void* d_out, int out_size, void* d_ws, size_t ws_size,
                              hipStream_t stream) {
    const float* x   = (const float*)d_in[0];
    const float* h   = (const float*)d_in[1];
    const float* c   = (const float*)d_in[2];
    const float* lap = (const float*)d_in[3];
    const int*   pos = (const int*)d_in[4];
    const float* Wfh = (const float*)d_in[5];
    const float* Wfx = (const float*)d_in[6];
    const float* bf  = (const float*)d_in[7];
    const float* Wih = (const float*)d_in[8];
    const float* Wix = (const float*)d_in[9];
    const float* bi  = (const float*)d_in[10];
    const float* Woh = (const float*)d_in[11];
    const float* Wox = (const float*)d_in[12];
    const float* bo  = (const float*)d_in[13];
    const float* Wch = (const float*)d_in[14];
    const float* Wcx = (const float*)d_in[15];
    const float* bc  = (const float*)d_in[16];
    float* out = (float*)d_out;

    uint8_t* ws = (uint8_t*)d_ws;
    size_t off = 0;
    auto take = [&](size_t bytes) -> void* {
        void* p = ws + off;
        off += (bytes + 255) & ~(size_t)255;
        return p;
    };
    uint32_t* hkey = (uint32_t*)take((size_t)TBL * 4);
    uint32_t* hidx = (uint32_t*)take((size_t)TBL * 4);
    int*      flag = (int*)take(4);
    uint32_t* rcnt = (uint32_t*)take((size_t)NN * 4);
    uint32_t* rptr = (uint32_t*)take((size_t)(NN + 1) * 4);
    uint32_t* curs = (uint32_t*)take((size_t)NN * 4);
    uint2*    cpack= (uint2*)take((size_t)EE * 8);
    unsigned short* Hb = (unsigned short*)take((size_t)3 * NN * HH * 2);  // levels 0..2
    unsigned short* Xb = (unsigned short*)take((size_t)3 * NN * II * 2);
    unsigned short* Amat = (unsigned short*)take((size_t)NN * KW * 2);    // 25.2 MB
    __hip_bfloat16* Bmat = (__hip_bfloat16*)take((size_t)MW * KW * 2);    //  3.1 MB

    init_ws<<<TBL / 256, 256, 0, stream>>>(hkey, hidx, rcnt, pos, flag);
    build_hash<<<EE / 256, 256, 0, stream>>>(pos, flag, hkey, hidx, rcnt);
    scan_rows<<<1, 1024, 0, stream>>>(rcnt, rptr, curs);
    scatter_csr<<<EE / 256, 256, 0, stream>>>(pos, flag, lap, hkey, hidx, curs, cpack);

    pack_T0<<<(NN * 96 + 255) / 256, 256, 0, stream>>>(h, x, Hb, Xb, Amat);
    pack_B<<<(MW * KW + 255) / 256, 256, 0, stream>>>(Wfh, Wih, Woh, Wch,
                                                      Wfx, Wix, Wox, Wcx, Bmat);

    unsigned short* Hb0 = Hb;
    unsigned short* Hb1 = Hb + (size_t)NN * HH;
    unsigned short* Hb2 = Hb1 + (size_t)NN * HH;
    unsigned short* Xb0 = Xb;
    unsigned short* Xb1 = Xb + (size_t)NN * II;
    unsigned short* Xb2 = Xb1 + (size_t)NN * II;

    int sg = NBH + NBX;   // 1024 + 512 blocks
    // level 1: T1 = L@T0
    spmv_cheb_dual<false><<<sg, 256, 0, stream>>>(rptr, cpack,
        Hb0, Hb0, Hb1, 256, Xb0, Xb0, Xb1, 1152, Amat, 1.0f, 0.0f);
    // level 2: T2 = 2 L@T1 - T0
    spmv_cheb_dual<false><<<sg, 256, 0, stream>>>(rptr, cpack,
        Hb1, Hb0, Hb2, 512, Xb1, Xb0, Xb2, 1280, Amat, 2.0f, -1.0f);
    // level 3: T3 = 2 L@T2 - T1 (A-matrix only)
    spmv_cheb_dual<true><<<sg, 256, 0, stream>>>(rptr, cpack,
        Hb2, Hb1, nullptr, 768, Xb2, Xb1, nullptr, 1408, Amat, 2.0f, -1.0f);

    gemm_fused<<<512, 256, 0, stream>>>((const __hip_bfloat16*)Amat, Bmat,
                                        bf, bi, bo, bc, c, out);
}